// Round 4
// baseline (232.941 us; speedup 1.0000x reference)
//
#include <hip/hip_runtime.h>

// SoftEmbeddedDecisionRules: balanced binary hierarchy over C=1024 classes.
// out[b,c] = prod over 10 levels of softmax-over-2-children prob of the branch
// containing c; child logit = mean of raw logits over the child's block;
// softmax over 2 == sigmoid(diff of means).
//
// R4: ONE WAVE PER ROW. Lane owns 16 contiguous classes (4x float4 loads in
// flight per lane -> 4x the memory-level parallelism of the one-load-per-thread
// version, probing the load-ILP-limited hypothesis). Levels seg=1..8 entirely
// in registers; seg=16..512 via 6-step __shfl_xor butterfly. ZERO barriers,
// ZERO LDS. 21 sigmoids per 16 outputs (vs 11 per 4 before).

#define C 1024

__device__ __forceinline__ float sigmoid_of(float x) {
    // 1 / (1 + exp(x)); v_rcp_f32 approx (~1e-7 rel err, absmax budget 3e-5)
    return __builtin_amdgcn_rcpf(1.0f + __expf(x));
}

__global__ __launch_bounds__(256) void hier_softmax_kernel(
    const float* __restrict__ in, float* __restrict__ out) {
    const int tid  = threadIdx.x;
    const int lane = tid & 63;
    const int wave = tid >> 6;
    const int row  = (blockIdx.x << 2) + wave;   // 4 rows per 256-thread block

    // 4 independent 16B loads issued back-to-back (stride 64B across lanes;
    // the 4 loads together cover the wave's contiguous 4KiB span line-complete)
    const float4* src = (const float4*)(in + (size_t)row * C + lane * 16);
    const float4 a = src[0], b = src[1], c = src[2], d = src[3];

    const float v[16] = {a.x, a.y, a.z, a.w, b.x, b.y, b.z, b.w,
                         c.x, c.y, c.z, c.w, d.x, d.y, d.z, d.w};

    // ---- in-register tree over this lane's 16 classes (levels seg=1,2,4,8) ----
    float s2[8], s4[4], s8[2], p1[8], p2[4], p4[2];
#pragma unroll
    for (int i = 0; i < 8; ++i) {
        s2[i] = v[2 * i] + v[2 * i + 1];
        p1[i] = sigmoid_of(v[2 * i + 1] - v[2 * i]);       // seg=1: p(even class)
    }
#pragma unroll
    for (int i = 0; i < 4; ++i) {
        s4[i] = s2[2 * i] + s2[2 * i + 1];
        p2[i] = sigmoid_of((s2[2 * i + 1] - s2[2 * i]) * 0.5f);
    }
#pragma unroll
    for (int i = 0; i < 2; ++i) {
        s8[i] = s4[2 * i] + s4[2 * i + 1];
        p4[i] = sigmoid_of((s4[2 * i + 1] - s4[2 * i]) * 0.25f);
    }
    const float p8 = sigmoid_of((s8[1] - s8[0]) * 0.125f);
    float sum = s8[0] + s8[1];                              // my 16-class sum

    // ---- levels seg=16..512: butterfly across the wave's 64 lanes ----
    // step k: partner lane (lane^k) holds the sibling block's sum;
    // p(my branch) = 1/(1+exp((mean_sib - mean_mine))) = sigmoid_of((part-sum)/seg)
    float common = 1.0f;
    float inv_seg = 1.0f / 16.0f;
#pragma unroll
    for (int k = 1; k <= 32; k <<= 1) {
        const float partner = __shfl_xor(sum, k, 64);
        common *= sigmoid_of((partner - sum) * inv_seg);
        sum += partner;
        inv_seg *= 0.5f;
    }

    // ---- product tree back down to the 16 class probs ----
    const float t8L = common * p8, t8R = common - t8L;
    float t4[4];
    t4[0] = t8L * p4[0]; t4[1] = t8L - t4[0];
    t4[2] = t8R * p4[1]; t4[3] = t8R - t4[2];
    float t2[8];
#pragma unroll
    for (int i = 0; i < 4; ++i) {
        t2[2 * i]     = t4[i] * p2[i];
        t2[2 * i + 1] = t4[i] - t2[2 * i];
    }
    float o[16];
#pragma unroll
    for (int i = 0; i < 8; ++i) {
        o[2 * i]     = t2[i] * p1[i];
        o[2 * i + 1] = t2[i] - o[2 * i];
    }

    float4* dst = (float4*)(out + (size_t)row * C + lane * 16);
    dst[0] = make_float4(o[0],  o[1],  o[2],  o[3]);
    dst[1] = make_float4(o[4],  o[5],  o[6],  o[7]);
    dst[2] = make_float4(o[8],  o[9],  o[10], o[11]);
    dst[3] = make_float4(o[12], o[13], o[14], o[15]);
}

extern "C" void kernel_launch(void* const* d_in, const int* in_sizes, int n_in,
                              void* d_out, int out_size, void* d_ws, size_t ws_size,
                              hipStream_t stream) {
    const float* in = (const float*)d_in[0];
    float* out = (float*)d_out;
    const int B = in_sizes[0] / C;      // 32768 rows
    hier_softmax_kernel<<<B / 4, 256, 0, stream>>>(in, out);
}

// Round 5
// 228.139 us; speedup vs baseline: 1.0210x; 1.0210x over previous
//
#include <hip/hip_runtime.h>

// SoftEmbeddedDecisionRules: balanced binary hierarchy over C=1024 classes.
// out[b,c] = prod over 10 levels of softmax-over-2-children prob of the branch
// containing c; child logit = mean of raw logits over the child's block;
// softmax over 2 == sigmoid(diff of means).
//
// R5: wave-per-row with QUARTER-INTERLEAVED lane ownership.
// Lane l owns classes q*256 + l*4 .. +3 for q=0..3, so each of its 4 loads is
// a fully CONTIGUOUS 1KiB wave access (lane*16B within quarter q) -- fixes
// R4's stride-64B pattern that degenerated coalescing (82us, 31% HBM, all
// pipes idle). Keeps R4's wins: 4 loads in flight per lane, ZERO barriers,
// ZERO LDS (top two tree levels are lane-local math on the 4 quarter totals).

#define C 1024

__device__ __forceinline__ float sigmoid_of(float x) {
    // 1 / (1 + exp(x)); v_rcp_f32 approx (~1e-7 rel err, absmax budget 3e-5)
    return __builtin_amdgcn_rcpf(1.0f + __expf(x));
}

__global__ __launch_bounds__(256) void hier_softmax_kernel(
    const float* __restrict__ in, float* __restrict__ out) {
    const int tid  = threadIdx.x;
    const int lane = tid & 63;
    const int wave = tid >> 6;
    const int row  = (blockIdx.x << 2) + wave;   // 4 independent rows per block

    const float* rowp = in + (size_t)row * C;

    // 4 independent, per-instruction-contiguous 1KiB wave loads (all in flight)
    float4 L[4];
    L[0] = ((const float4*)(rowp +   0))[lane];
    L[1] = ((const float4*)(rowp + 256))[lane];
    L[2] = ((const float4*)(rowp + 512))[lane];
    L[3] = ((const float4*)(rowp + 768))[lane];

    // ---- per-quarter register tree (levels seg=1, seg=2) ----
    float pA[4], pB[4], p2[4], sum[4], com[4];
#pragma unroll
    for (int q = 0; q < 4; ++q) {
        const float s2a = L[q].x + L[q].y;
        const float s2b = L[q].z + L[q].w;
        pA[q]  = sigmoid_of(L[q].y - L[q].x);          // p(even class of pair)
        pB[q]  = sigmoid_of(L[q].w - L[q].z);
        p2[q]  = sigmoid_of((s2b - s2a) * 0.5f);       // p(left pair)
        sum[q] = s2a + s2b;                            // lane's 4-class block sum
        com[q] = 1.0f;
    }

    // ---- levels seg=4..128: butterfly over lanes, all 4 quarters interleaved
    // step k: lane^k holds the sibling block's sum within each quarter.
    float inv_seg = 0.25f;
#pragma unroll
    for (int k = 1; k <= 32; k <<= 1) {
        float pr[4];
#pragma unroll
        for (int q = 0; q < 4; ++q) pr[q] = __shfl_xor(sum[q], k, 64);
#pragma unroll
        for (int q = 0; q < 4; ++q) {
            com[q] *= sigmoid_of((pr[q] - sum[q]) * inv_seg);
            sum[q] += pr[q];
        }
        inv_seg *= 0.5f;
    }
    // sum[q] == quarter-q total (identical across lanes)

    // ---- top two levels (seg=256, seg=512), lane-local ----
    const float pRoot = sigmoid_of((sum[2] + sum[3] - sum[0] - sum[1]) * (1.0f / 512.0f));
    const float pL    = sigmoid_of((sum[1] - sum[0]) * (1.0f / 256.0f));
    const float pR    = sigmoid_of((sum[3] - sum[2]) * (1.0f / 256.0f));
    float t[4];
    t[0] = pRoot * pL;          t[1] = pRoot - t[0];
    const float rRoot = 1.0f - pRoot;
    t[2] = rRoot * pR;          t[3] = rRoot - t[2];

    // ---- downsweep + 4 contiguous 1KiB wave stores ----
    float* orow = out + (size_t)row * C;
#pragma unroll
    for (int q = 0; q < 4; ++q) {
        const float base = t[q] * com[q];
        const float cl = base * p2[q];
        const float cr = base - cl;
        float4 o;
        o.x = cl * pA[q];
        o.y = cl - o.x;
        o.z = cr * pB[q];
        o.w = cr - o.z;
        ((float4*)(orow + q * 256))[lane] = o;
    }
}

extern "C" void kernel_launch(void* const* d_in, const int* in_sizes, int n_in,
                              void* d_out, int out_size, void* d_ws, size_t ws_size,
                              hipStream_t stream) {
    const float* in = (const float*)d_in[0];
    float* out = (float*)d_out;
    const int B = in_sizes[0] / C;      // 32768 rows
    hier_softmax_kernel<<<B / 4, 256, 0, stream>>>(in, out);
}